// Round 2
// baseline (116.653 us; speedup 1.0000x reference)
//
#include <hip/hip_runtime.h>
#include <math.h>

#define N_NODES 10000
#define N_EDGES 160000
#define CAP 64                     // bucket capacity per node (Poisson(16), P(deg>64) ~ 1e-19)

// R10: 4-dispatch chain (was 5).
// Pass-1 (s1,deg) no longer needs the buckets: it is folded into the
// bucket-build kernel as fire-and-forget global f32 atomics (320K adds to
// 20K L2-resident addresses, avg 16 contenders -- pipelined). The bucket CSR
// is kept for pass-2 and the A-pass (pure coalesced gathers, no contention).
// Dense chain (u,v -> p,q,r) stays spread across otherwise-idle blocks of
// D0/D1/D2 so it is entirely latency-hidden.
//   D0 (k0): zero cnt + zero sd + u,v partials        (u=W1@W2, v=b1@W2)
//   D1 (k1): bucket fill + s1/deg atomic scatter + p,q,r partials
//   D2 (k2): pass2 from buckets -> t2, Bf; p,q,r final
//   D3 (k3): output (A-pass prologue from buckets + 10000x512 expansion)
//
// Workspace layout (floats):
//   [0      .. 10000)   cnt (int)          per-node slot counters
//   [10240  .. 30240)   sd  float2(s1,deg) -- atomically accumulated in D1
//   [30240  .. 40240)   t2
//   [40240  .. 50240)   Bf
//   [50240  .. 50752)   p
//   [50752  .. 51264)   q
//   [51264  .. 51776)   r
//   [51776  .. 55872)   u_part[16][256]
//   [55872  .. 59968)   v_part[16][256]
//   [60000  .. 68192)   p_part[16][512]
//   [68192  .. 76384)   q_part[16][512]
//   [76384  .. 84576)   r_part[16][512]
//   [84576  .. 1364576) bucket[10000][64] float2(src_bits, ew)

// ---------- D0: zero cnt + zero sd + u/v partials --------------------------
__global__ __launch_bounds__(512) void k0_kernel(
        int* __restrict__ cnt, float* __restrict__ sdf,
        const float* __restrict__ W1, const float* __restrict__ b1,
        const float* __restrict__ W2,
        float* __restrict__ u_part, float* __restrict__ v_part) {
    int tid = threadIdx.x;
    int blk = blockIdx.x;
    if (blk == 0) {
        for (int g = tid; g < N_NODES / 4; g += 512)
            ((int4*)cnt)[g] = make_int4(0, 0, 0, 0);
    } else if (blk == 1) {
        for (int g = tid; g < 2 * N_NODES / 4; g += 512)
            ((float4*)sdf)[g] = make_float4(0.f, 0.f, 0.f, 0.f);
    } else {
        int b = blk - 2;                 // 0..15, j-chunk [8b, 8b+8)
        if (tid < 256) {
            int j0 = b * 8;
            float uu = 0.f, vv = 0.f;
            #pragma unroll
            for (int jj = 0; jj < 8; ++jj) {
                float w2 = W2[(j0 + jj) * 256 + tid];   // coalesced
                uu = fmaf(W1[j0 + jj], w2, uu);
                vv = fmaf(b1[j0 + jj], w2, vv);
            }
            u_part[b * 256 + tid] = uu;
            v_part[b * 256 + tid] = vv;
        }
    }
}

// ---------- D1: bucket fill + s1/deg atomic scatter + p/q/r partials -------
// blocks 0..312: one edge per thread:
//   slot = atomicAdd(cnt[d]) -> 8B bucket store   (CSR for later passes)
//   atomicAdd(sd[d].x, w*x[s]); atomicAdd(sd[d].y, w)   (pass-1, f&f)
// blocks 313..328: p/q/r partial k-chunk (blk-313)
__global__ __launch_bounds__(512) void k1_kernel(
        const int* __restrict__ src, const int* __restrict__ dst,
        const float* __restrict__ ew, const float* __restrict__ x,
        int* __restrict__ cnt, float2* __restrict__ bucket,
        float* __restrict__ sdf,
        const float* __restrict__ u_part, const float* __restrict__ v_part,
        const float* __restrict__ b2, const float* __restrict__ W3,
        float* __restrict__ p_part, float* __restrict__ q_part,
        float* __restrict__ r_part) {
    int tid = threadIdx.x;
    int blk = blockIdx.x;
    if (blk < 313) {
        int e = blk * 512 + tid;
        if (e < N_EDGES) {
            int   s = src[e];
            int   d = dst[e];
            float w = ew[e];
            float xs = x[s];                    // 40KB, L2-resident gather
            int slot = atomicAdd(&cnt[d], 1);
            if (slot < CAP)
                bucket[d * CAP + slot] = make_float2(__int_as_float(s), w);
            atomicAdd(&sdf[2 * d],     w * xs); // s1
            atomicAdd(&sdf[2 * d + 1], w);      // deg
        }
    } else {
        int c = blk - 313;               // 0..15, k-chunk [16c,16c+16)
        __shared__ float su[16], sv[16], sb[16];
        if (tid < 16) {
            int kk = c * 16 + tid;
            float uu = 0.f, vv = 0.f;
            #pragma unroll
            for (int b = 0; b < 16; ++b) {
                uu += u_part[b * 256 + kk];
                vv += v_part[b * 256 + kk];
            }
            su[tid] = uu; sv[tid] = vv; sb[tid] = b2[kk];
        }
        __syncthreads();
        float pp = 0.f, qq = 0.f, rr = 0.f;
        #pragma unroll
        for (int kk = 0; kk < 16; ++kk) {
            float w3 = W3[(c * 16 + kk) * 512 + tid];   // coalesced
            pp = fmaf(su[kk], w3, pp);
            qq = fmaf(sv[kk], w3, qq);
            rr = fmaf(sb[kk], w3, rr);
        }
        p_part[c * 512 + tid] = pp;
        q_part[c * 512 + tid] = qq;
        r_part[c * 512 + tid] = rr;
    }
}

// ---------- D2: pass2 gather -> t2, Bf; p/q/r final ------------------------
// blocks 0..312: 16 lanes per node, bucket gather + shfl reduce
// block 313: p/q/r 16-way final reduce
__global__ __launch_bounds__(512) void k2_kernel(
        const int* __restrict__ cnt, const float2* __restrict__ bucket,
        const float2* __restrict__ sd,
        float* __restrict__ t2, float* __restrict__ Bf,
        const float* __restrict__ p_part, const float* __restrict__ q_part,
        const float* __restrict__ r_part,
        float* __restrict__ p, float* __restrict__ q, float* __restrict__ r) {
    int tid = threadIdx.x;
    int blk = blockIdx.x;
    if (blk < 313) {
        int gid = blk * 512 + tid;
        int n = gid >> 4;                // node
        int l = gid & 15;                // lane within node group
        if (n < N_NODES) {
            int c = cnt[n]; if (c > CAP) c = CAP;
            float tt = 0.f, bb = 0.f;
            for (int i = l; i < c; i += 16) {
                float2 e = bucket[n * CAP + i];      // 128B/node, coalesced
                float2 v = sd[__float_as_int(e.x)];  // gather (s1, deg)
                tt = fmaf(e.y, v.x, tt);
                bb = fmaf(e.y, v.y, bb);
            }
            #pragma unroll
            for (int m = 1; m < 16; m <<= 1) {
                tt += __shfl_xor(tt, m);
                bb += __shfl_xor(bb, m);
            }
            if (l == 0) { t2[n] = tt; Bf[n] = bb; }
        }
    } else {
        float pp = 0.f, qq = 0.f, rr = 0.f;
        #pragma unroll
        for (int c2 = 0; c2 < 16; ++c2) {
            pp += p_part[c2 * 512 + tid];
            qq += q_part[c2 * 512 + tid];
            rr += r_part[c2 * 512 + tid];
        }
        p[tid] = pp; q[tid] = qq; r[tid] = rr;
    }
}

// ---------- D3: output (A-pass prologue + expansion) -----------------------
// 625 blocks x 256 threads; block = 16 nodes x 128 float4 columns.
// Prologue computes A[n] = sum(ew * t2[src]) over the node's own bucket.
__global__ __launch_bounds__(256) void output_kernel(
        const int* __restrict__ cnt, const float2* __restrict__ bucket,
        const float* __restrict__ t2, const float* __restrict__ Bf,
        const float2* __restrict__ sd,
        const float* __restrict__ p, const float* __restrict__ q,
        const float* __restrict__ r, const float* __restrict__ b3,
        float* __restrict__ out) {
    int tid = threadIdx.x;
    int n0 = blockIdx.x * 16;
    __shared__ float A_l[16], B_l[16], D_l[16];
    {
        int nl = tid >> 4;               // local node 0..15
        int l = tid & 15;                // lane within node group
        int n = n0 + nl;
        int c = cnt[n]; if (c > CAP) c = CAP;
        float acc = 0.f;
        for (int i = l; i < c; i += 16) {
            float2 e = bucket[n * CAP + i];
            acc = fmaf(e.y, t2[__float_as_int(e.x)], acc);
        }
        #pragma unroll
        for (int m = 1; m < 16; m <<= 1) acc += __shfl_xor(acc, m);
        if (l == 0) {
            A_l[nl] = acc;
            B_l[nl] = Bf[n];
            D_l[nl] = sd[n].y;           // deg
        }
    }
    __syncthreads();
    #pragma unroll
    for (int h = 0; h < 8; ++h) {
        int idx = h * 256 + tid;         // 0..2047 within block
        int nl = idx >> 7;               // local node 0..15
        int j = idx & 127;               // float4 column
        float a = A_l[nl], b = B_l[nl], dg = D_l[nl];
        float4 P = ((const float4*)p)[j];
        float4 Q = ((const float4*)q)[j];
        float4 R = ((const float4*)r)[j];
        float4 B3 = ((const float4*)b3)[j];
        float4 o;
        float zx = fmaf(a, P.x, fmaf(b, Q.x, fmaf(dg, R.x, B3.x)));
        float zy = fmaf(a, P.y, fmaf(b, Q.y, fmaf(dg, R.y, B3.y)));
        float zz = fmaf(a, P.z, fmaf(b, Q.z, fmaf(dg, R.z, B3.z)));
        float zw = fmaf(a, P.w, fmaf(b, Q.w, fmaf(dg, R.w, B3.w)));
        o.x = 1.f / (1.f + __expf(-zx));
        o.y = 1.f / (1.f + __expf(-zy));
        o.z = 1.f / (1.f + __expf(-zz));
        o.w = 1.f / (1.f + __expf(-zw));
        ((float4*)out)[(size_t)(n0 + nl) * 128 + j] = o;
    }
}

extern "C" void kernel_launch(void* const* d_in, const int* in_sizes, int n_in,
                              void* d_out, int out_size, void* d_ws, size_t ws_size,
                              hipStream_t stream) {
    const float* x  = (const float*)d_in[0];
    const int*   ei = (const int*)d_in[1];
    const float* ew = (const float*)d_in[2];
    const float* W1 = (const float*)d_in[3];
    const float* b1 = (const float*)d_in[4];
    const float* W2 = (const float*)d_in[5];
    const float* b2 = (const float*)d_in[6];
    const float* W3 = (const float*)d_in[7];
    const float* b3 = (const float*)d_in[8];
    float* out = (float*)d_out;

    float* ws       = (float*)d_ws;
    int*    cnt     = (int*)ws;                    // 10000 ints
    float*  sdf     = ws + 10240;                  // 10000 float2, atomic acc
    float2* sd      = (float2*)sdf;
    float*  t2      = ws + 30240;
    float*  Bf      = ws + 40240;
    float*  p       = ws + 50240;
    float*  q       = ws + 50752;
    float*  r       = ws + 51264;
    float*  u_part  = ws + 51776;
    float*  v_part  = ws + 55872;
    float*  p_part  = ws + 60000;
    float*  q_part  = ws + 68192;
    float*  r_part  = ws + 76384;
    float2* bucket  = (float2*)(ws + 84576);       // 10000 x 64 float2

    const int* src = ei;            // edge_index[0]
    const int* dst = ei + N_EDGES;  // edge_index[1]

    k0_kernel<<<18, 512, 0, stream>>>(cnt, sdf, W1, b1, W2, u_part, v_part);
    k1_kernel<<<329, 512, 0, stream>>>(src, dst, ew, x, cnt, bucket, sdf,
                                       u_part, v_part, b2, W3,
                                       p_part, q_part, r_part);
    k2_kernel<<<314, 512, 0, stream>>>(cnt, bucket, sd, t2, Bf,
                                       p_part, q_part, r_part, p, q, r);
    output_kernel<<<625, 256, 0, stream>>>(cnt, bucket, t2, Bf, sd,
                                           p, q, r, b3, out);
}

// Round 3
// 114.825 us; speedup vs baseline: 1.0159x; 1.0159x over previous
//
#include <hip/hip_runtime.h>
#include <math.h>

#define N_NODES 10000
#define N_EDGES 160000
#define CAP 64      // bucket capacity per node (Poisson(16), P(deg>64) ~ 1e-19)
#define PAD 16      // floats per node in padded sd array (64B: private cache line)

// R11: 4-dispatch chain, de-contended pass-1 atomics.
// R10 post-mortem: folding pass-1 (s1,deg) into the bucket-build as global f32
// atomics regressed 103.5 -> 116.7 us. Theory: sd was packed float2 -> 8 nodes
// per 64B line -> ~128 serialized same-line RMWs at the memory-side cache; the
// kernel waits on the deepest line queue. Fix: pad to 64B per node (sdp[n*16]),
// 4x fewer ops per line, 8x more lines. Costs one 640KB zero (hidden in k0).
//   D0 (k0): zero cnt + zero sdp + u,v partials       (u=W1@W2, v=b1@W2)
//   D1 (k1): bucket fill + s1/deg padded-atomic scatter + p,q,r partials
//   D2 (k2): pass2 from buckets -> t2, Bf; p,q,r final
//   D3 (k3): output (A-pass prologue from buckets + 10000x512 expansion)
//
// Workspace layout (floats):
//   [0       .. 10000)    cnt (int)        per-node slot counters
//   [10240   .. 170240)   sdp[10000][16]   (s1, deg) in first 2 floats, 64B/node
//   [170240  .. 180240)   t2
//   [180240  .. 190240)   Bf
//   [190240  .. 190752)   p
//   [190752  .. 191264)   q
//   [191264  .. 191776)   r
//   [191776  .. 195872)   u_part[16][256]
//   [195872  .. 199968)   v_part[16][256]
//   [200000  .. 208192)   p_part[16][512]
//   [208192  .. 216384)   q_part[16][512]
//   [216384  .. 224576)   r_part[16][512]
//   [224576  .. 1504576)  bucket[10000][64] float2(src_bits, ew)

// ---------- D0: zero cnt + zero sdp + u/v partials -------------------------
__global__ __launch_bounds__(512) void k0_kernel(
        int* __restrict__ cnt, float* __restrict__ sdp,
        const float* __restrict__ W1, const float* __restrict__ b1,
        const float* __restrict__ W2,
        float* __restrict__ u_part, float* __restrict__ v_part) {
    int tid = threadIdx.x;
    int blk = blockIdx.x;
    if (blk < 10) {
        // zero sdp: 160000 floats = 40000 float4, 4000 per block
        float4* dst4 = (float4*)sdp + blk * 4000;
        for (int g = tid; g < 4000; g += 512)
            dst4[g] = make_float4(0.f, 0.f, 0.f, 0.f);
    } else if (blk == 10) {
        for (int g = tid; g < N_NODES / 4; g += 512)
            ((int4*)cnt)[g] = make_int4(0, 0, 0, 0);
    } else {
        int b = blk - 11;                // 0..15, j-chunk [8b, 8b+8)
        if (tid < 256) {
            int j0 = b * 8;
            float uu = 0.f, vv = 0.f;
            #pragma unroll
            for (int jj = 0; jj < 8; ++jj) {
                float w2 = W2[(j0 + jj) * 256 + tid];   // coalesced
                uu = fmaf(W1[j0 + jj], w2, uu);
                vv = fmaf(b1[j0 + jj], w2, vv);
            }
            u_part[b * 256 + tid] = uu;
            v_part[b * 256 + tid] = vv;
        }
    }
}

// ---------- D1: bucket fill + padded s1/deg scatter + p/q/r partials -------
// blocks 0..312: one edge per thread:
//   atomicAdd(sdp[d*16], w*x[s]); atomicAdd(sdp[d*16+1], w)   (pass-1, f&f)
//   slot = atomicAdd(cnt[d]) -> 8B bucket store   (CSR for later passes)
// blocks 313..328: p/q/r partial k-chunk (blk-313)
__global__ __launch_bounds__(512) void k1_kernel(
        const int* __restrict__ src, const int* __restrict__ dst,
        const float* __restrict__ ew, const float* __restrict__ x,
        int* __restrict__ cnt, float2* __restrict__ bucket,
        float* __restrict__ sdp,
        const float* __restrict__ u_part, const float* __restrict__ v_part,
        const float* __restrict__ b2, const float* __restrict__ W3,
        float* __restrict__ p_part, float* __restrict__ q_part,
        float* __restrict__ r_part) {
    int tid = threadIdx.x;
    int blk = blockIdx.x;
    if (blk < 313) {
        int e = blk * 512 + tid;
        if (e < N_EDGES) {
            int   s = src[e];
            int   d = dst[e];
            float w = ew[e];
            float xs = x[s];                     // 40KB, cache-resident gather
            atomicAdd(&sdp[d * PAD],     w * xs);   // s1  (f&f, private line)
            atomicAdd(&sdp[d * PAD + 1], w);        // deg (f&f, same line)
            int slot = atomicAdd(&cnt[d], 1);
            if (slot < CAP)
                bucket[d * CAP + slot] = make_float2(__int_as_float(s), w);
        }
    } else {
        int c = blk - 313;               // 0..15, k-chunk [16c,16c+16)
        __shared__ float su[16], sv[16], sb[16];
        if (tid < 16) {
            int kk = c * 16 + tid;
            float uu = 0.f, vv = 0.f;
            #pragma unroll
            for (int b = 0; b < 16; ++b) {
                uu += u_part[b * 256 + kk];
                vv += v_part[b * 256 + kk];
            }
            su[tid] = uu; sv[tid] = vv; sb[tid] = b2[kk];
        }
        __syncthreads();
        float pp = 0.f, qq = 0.f, rr = 0.f;
        #pragma unroll
        for (int kk = 0; kk < 16; ++kk) {
            float w3 = W3[(c * 16 + kk) * 512 + tid];   // coalesced
            pp = fmaf(su[kk], w3, pp);
            qq = fmaf(sv[kk], w3, qq);
            rr = fmaf(sb[kk], w3, rr);
        }
        p_part[c * 512 + tid] = pp;
        q_part[c * 512 + tid] = qq;
        r_part[c * 512 + tid] = rr;
    }
}

// ---------- D2: pass2 gather -> t2, Bf; p/q/r final ------------------------
// blocks 0..312: 16 lanes per node, bucket gather + shfl reduce
// block 313: p/q/r 16-way final reduce
__global__ __launch_bounds__(512) void k2_kernel(
        const int* __restrict__ cnt, const float2* __restrict__ bucket,
        const float* __restrict__ sdp,
        float* __restrict__ t2, float* __restrict__ Bf,
        const float* __restrict__ p_part, const float* __restrict__ q_part,
        const float* __restrict__ r_part,
        float* __restrict__ p, float* __restrict__ q, float* __restrict__ r) {
    int tid = threadIdx.x;
    int blk = blockIdx.x;
    if (blk < 313) {
        int gid = blk * 512 + tid;
        int n = gid >> 4;                // node
        int l = gid & 15;                // lane within node group
        if (n < N_NODES) {
            int c = cnt[n]; if (c > CAP) c = CAP;
            float tt = 0.f, bb = 0.f;
            for (int i = l; i < c; i += 16) {
                float2 e = bucket[n * CAP + i];      // 128B/node, coalesced
                float2 v = *(const float2*)&sdp[__float_as_int(e.x) * PAD];
                tt = fmaf(e.y, v.x, tt);
                bb = fmaf(e.y, v.y, bb);
            }
            #pragma unroll
            for (int m = 1; m < 16; m <<= 1) {
                tt += __shfl_xor(tt, m);
                bb += __shfl_xor(bb, m);
            }
            if (l == 0) { t2[n] = tt; Bf[n] = bb; }
        }
    } else {
        float pp = 0.f, qq = 0.f, rr = 0.f;
        #pragma unroll
        for (int c2 = 0; c2 < 16; ++c2) {
            pp += p_part[c2 * 512 + tid];
            qq += q_part[c2 * 512 + tid];
            rr += r_part[c2 * 512 + tid];
        }
        p[tid] = pp; q[tid] = qq; r[tid] = rr;
    }
}

// ---------- D3: output (A-pass prologue + expansion) -----------------------
// 625 blocks x 256 threads; block = 16 nodes x 128 float4 columns.
// Prologue computes A[n] = sum(ew * t2[src]) over the node's own bucket.
__global__ __launch_bounds__(256) void output_kernel(
        const int* __restrict__ cnt, const float2* __restrict__ bucket,
        const float* __restrict__ t2, const float* __restrict__ Bf,
        const float* __restrict__ sdp,
        const float* __restrict__ p, const float* __restrict__ q,
        const float* __restrict__ r, const float* __restrict__ b3,
        float* __restrict__ out) {
    int tid = threadIdx.x;
    int n0 = blockIdx.x * 16;
    __shared__ float A_l[16], B_l[16], D_l[16];
    {
        int nl = tid >> 4;               // local node 0..15
        int l = tid & 15;                // lane within node group
        int n = n0 + nl;
        int c = cnt[n]; if (c > CAP) c = CAP;
        float acc = 0.f;
        for (int i = l; i < c; i += 16) {
            float2 e = bucket[n * CAP + i];
            acc = fmaf(e.y, t2[__float_as_int(e.x)], acc);
        }
        #pragma unroll
        for (int m = 1; m < 16; m <<= 1) acc += __shfl_xor(acc, m);
        if (l == 0) {
            A_l[nl] = acc;
            B_l[nl] = Bf[n];
            D_l[nl] = sdp[n * PAD + 1];  // deg
        }
    }
    __syncthreads();
    #pragma unroll
    for (int h = 0; h < 8; ++h) {
        int idx = h * 256 + tid;         // 0..2047 within block
        int nl = idx >> 7;               // local node 0..15
        int j = idx & 127;               // float4 column
        float a = A_l[nl], b = B_l[nl], dg = D_l[nl];
        float4 P = ((const float4*)p)[j];
        float4 Q = ((const float4*)q)[j];
        float4 R = ((const float4*)r)[j];
        float4 B3 = ((const float4*)b3)[j];
        float4 o;
        float zx = fmaf(a, P.x, fmaf(b, Q.x, fmaf(dg, R.x, B3.x)));
        float zy = fmaf(a, P.y, fmaf(b, Q.y, fmaf(dg, R.y, B3.y)));
        float zz = fmaf(a, P.z, fmaf(b, Q.z, fmaf(dg, R.z, B3.z)));
        float zw = fmaf(a, P.w, fmaf(b, Q.w, fmaf(dg, R.w, B3.w)));
        o.x = 1.f / (1.f + __expf(-zx));
        o.y = 1.f / (1.f + __expf(-zy));
        o.z = 1.f / (1.f + __expf(-zz));
        o.w = 1.f / (1.f + __expf(-zw));
        ((float4*)out)[(size_t)(n0 + nl) * 128 + j] = o;
    }
}

extern "C" void kernel_launch(void* const* d_in, const int* in_sizes, int n_in,
                              void* d_out, int out_size, void* d_ws, size_t ws_size,
                              hipStream_t stream) {
    const float* x  = (const float*)d_in[0];
    const int*   ei = (const int*)d_in[1];
    const float* ew = (const float*)d_in[2];
    const float* W1 = (const float*)d_in[3];
    const float* b1 = (const float*)d_in[4];
    const float* W2 = (const float*)d_in[5];
    const float* b2 = (const float*)d_in[6];
    const float* W3 = (const float*)d_in[7];
    const float* b3 = (const float*)d_in[8];
    float* out = (float*)d_out;

    float* ws       = (float*)d_ws;
    int*    cnt     = (int*)ws;                    // 10000 ints
    float*  sdp     = ws + 10240;                  // 10000 x 16 floats, 64B/node
    float*  t2      = ws + 170240;
    float*  Bf      = ws + 180240;
    float*  p       = ws + 190240;
    float*  q       = ws + 190752;
    float*  r       = ws + 191264;
    float*  u_part  = ws + 191776;
    float*  v_part  = ws + 195872;
    float*  p_part  = ws + 200000;
    float*  q_part  = ws + 208192;
    float*  r_part  = ws + 216384;
    float2* bucket  = (float2*)(ws + 224576);      // 10000 x 64 float2

    const int* src = ei;            // edge_index[0]
    const int* dst = ei + N_EDGES;  // edge_index[1]

    k0_kernel<<<27, 512, 0, stream>>>(cnt, sdp, W1, b1, W2, u_part, v_part);
    k1_kernel<<<329, 512, 0, stream>>>(src, dst, ew, x, cnt, bucket, sdp,
                                       u_part, v_part, b2, W3,
                                       p_part, q_part, r_part);
    k2_kernel<<<314, 512, 0, stream>>>(cnt, bucket, sdp, t2, Bf,
                                       p_part, q_part, r_part, p, q, r);
    output_kernel<<<625, 256, 0, stream>>>(cnt, bucket, t2, Bf, sdp,
                                           p, q, r, b3, out);
}